// Round 6
// baseline (368.860 us; speedup 1.0000x reference)
//
#include <hip/hip_runtime.h>
#include <hip/hip_bf16.h>

// SeqAttention collapses algebraically:
//   alpha = softmax(e, axis=1); s = sum(alpha, axis=1)  ==>  s == 1 exactly
//   (softmax columns each sum to 1 over the axis being summed).
//   context[b,t] = sum_d hid[b,t,d] = x[b,t,:] . colsum(W) + sum(b)
// So: ws[0..D-1] = column sums of W (over rows d), ws[D] = sum(b),
// then out[row] = dot(x[row,:], ws[0:D]) + ws[D].
//
// Roofline: read x (256 MB) + W (4 MB) once, write 256 KB -> ~42 us at 6.3 TB/s.

constexpr int Bn = 32;
constexpr int Tn = 2048;
constexpr int Dn = 1024;
constexpr int ROWS = Bn * Tn;  // 65536

// ---- kernel 1: zero wcol accumulator + reduce bias sum ----
__global__ __launch_bounds__(256) void sa_init_kernel(const float* __restrict__ bvec,
                                                      float* __restrict__ ws) {
    if (blockIdx.x < 4) {
        int k = blockIdx.x * 256 + threadIdx.x;   // 0..1023
        ws[k] = 0.0f;
    } else {
        // block 4: bsum = sum(b[0..D-1])
        int t = threadIdx.x;
        float a = bvec[t] + bvec[t + 256] + bvec[t + 512] + bvec[t + 768];
        #pragma unroll
        for (int off = 32; off; off >>= 1) a += __shfl_xor(a, off, 64);
        __shared__ float s[4];
        if ((t & 63) == 0) s[t >> 6] = a;
        __syncthreads();
        if (t == 0) ws[Dn] = s[0] + s[1] + s[2] + s[3];
    }
}

// ---- kernel 2: wcol[k] = sum_d W[d*Dn + k], per-block partials + one atomic each ----
__global__ __launch_bounds__(256) void sa_colsum_kernel(const float* __restrict__ W,
                                                        float* __restrict__ ws) {
    // grid: 128 blocks x 256 threads; block handles 8 consecutive rows of W.
    int tid = threadIdx.x;                 // thread owns columns 4*tid .. 4*tid+3
    int r0 = blockIdx.x * 8;
    float4 acc = make_float4(0.f, 0.f, 0.f, 0.f);
    #pragma unroll
    for (int r = 0; r < 8; ++r) {
        const float4* row = reinterpret_cast<const float4*>(W + (size_t)(r0 + r) * Dn);
        float4 v = row[tid];               // coalesced 16B/lane
        acc.x += v.x; acc.y += v.y; acc.z += v.z; acc.w += v.w;
    }
    atomicAdd(&ws[4 * tid + 0], acc.x);
    atomicAdd(&ws[4 * tid + 1], acc.y);
    atomicAdd(&ws[4 * tid + 2], acc.z);
    atomicAdd(&ws[4 * tid + 3], acc.w);
}

// ---- kernel 3: out[row] = dot(x[row,:], wcol) + bsum ; one wave per row ----
__global__ __launch_bounds__(256) void sa_dot_kernel(const float* __restrict__ x,
                                                     const float* __restrict__ ws,
                                                     float* __restrict__ out) {
    int wave = (int)((blockIdx.x * (unsigned)blockDim.x + threadIdx.x) >> 6);
    int lane = threadIdx.x & 63;
    if (wave >= ROWS) return;

    const float4* xr = reinterpret_cast<const float4*>(x + (size_t)wave * Dn);
    const float4* wr = reinterpret_cast<const float4*>(ws);
    float acc = 0.0f;
    #pragma unroll
    for (int j = 0; j < 4; ++j) {
        float4 xv = xr[lane + j * 64];     // coalesced: 64 lanes x 16B contiguous
        float4 wv = wr[lane + j * 64];     // 4KB, L1-resident after first wave
        acc += xv.x * wv.x + xv.y * wv.y + xv.z * wv.z + xv.w * wv.w;
    }
    #pragma unroll
    for (int off = 32; off; off >>= 1) acc += __shfl_xor(acc, off, 64);
    if (lane == 0) out[wave] = acc + ws[Dn];
}

extern "C" void kernel_launch(void* const* d_in, const int* in_sizes, int n_in,
                              void* d_out, int out_size, void* d_ws, size_t ws_size,
                              hipStream_t stream) {
    const float* x = (const float*)d_in[0];   // [B,T,D] fp32
    const float* W = (const float*)d_in[1];   // [D,D]  fp32
    const float* b = (const float*)d_in[2];   // [D]    fp32
    float* out = (float*)d_out;               // [B,T]  fp32
    float* ws  = (float*)d_ws;                // needs (D+1) floats = 4100 B

    sa_init_kernel<<<5, 256, 0, stream>>>(b, ws);
    sa_colsum_kernel<<<Dn / 8, 256, 0, stream>>>(W, ws);
    sa_dot_kernel<<<ROWS / 4, 256, 0, stream>>>(x, ws, out);
}

// Round 7
// 335.457 us; speedup vs baseline: 1.0996x; 1.0996x over previous
//
#include <hip/hip_runtime.h>
#include <hip/hip_bf16.h>

// SeqAttention collapses algebraically:
//   alpha = softmax(e, axis=1); s = sum(alpha, axis=1)  ==>  s == 1 exactly
//   (softmax columns each sum to 1 over the axis being summed).
//   context[b,t] = sum_d hid[b,t,d] = x[b,t,:] . colsum(W) + sum(b)
// ws[0..D-1] = column sums of W, ws[D] = sum(b); out[row] = x[row,:].ws + ws[D].
//
// Roofline (kernel side): read x (256MB) + W (4MB), write 256KB -> ~42 us @ 6.3 TB/s.
// Measured total (R6: 368.9us) is dominated by harness reset fills (1GiB ws poison
// ~160us + input restore); kernel slice is the only controllable part.

constexpr int Dn = 1024;
constexpr int ROWS = 32 * 2048;  // 65536

typedef float v4f __attribute__((ext_vector_type(4)));

// ---- kernel 1 (fused): colsum(W) -> ws[0..1023], sum(b) -> ws[1024]. No atomics,
// no pre-zero needed: every ws element is written exactly once, non-atomically.
__global__ __launch_bounds__(256) void sa_prep_kernel(const float* __restrict__ W,
                                                      const float* __restrict__ bvec,
                                                      float* __restrict__ ws) {
    int blk = blockIdx.x;
    if (blk < 32) {
        // block owns 32 columns [32*blk, 32*blk+32) = 8 float4 slots per row
        int t  = threadIdx.x;
        int cq = t & 7;          // colquad 0..7 within slice
        int r0 = t >> 3;         // row phase 0..31
        const v4f* Wv = reinterpret_cast<const v4f*>(W);
        v4f acc = {0.f, 0.f, 0.f, 0.f};
        #pragma unroll 4
        for (int r = r0; r < Dn; r += 32) {
            acc += Wv[r * (Dn / 4) + blk * 8 + cq];
        }
        __shared__ v4f part[256];
        part[t] = acc;
        __syncthreads();
        if (t < 8) {             // t == colquad
            v4f s = {0.f, 0.f, 0.f, 0.f};
            #pragma unroll
            for (int i = 0; i < 32; ++i) s += part[t + i * 8];
            reinterpret_cast<v4f*>(ws)[blk * 8 + t] = s;
        }
    } else {
        // block 32: bsum
        int t = threadIdx.x;
        float a = bvec[t] + bvec[t + 256] + bvec[t + 512] + bvec[t + 768];
        #pragma unroll
        for (int off = 32; off; off >>= 1) a += __shfl_xor(a, off, 64);
        __shared__ float s4[4];
        if ((t & 63) == 0) s4[t >> 6] = a;
        __syncthreads();
        if (t == 0) ws[Dn] = s4[0] + s4[1] + s4[2] + s4[3];
    }
}

// ---- kernel 2: out[row] = dot(x[row,:], wcol) + bsum ; one wave per row ----
__global__ __launch_bounds__(256) void sa_dot_kernel(const float* __restrict__ x,
                                                     const float* __restrict__ ws,
                                                     float* __restrict__ out) {
    int wave = (int)((blockIdx.x * (unsigned)blockDim.x + threadIdx.x) >> 6);
    int lane = threadIdx.x & 63;
    if (wave >= ROWS) return;

    const v4f* xr = reinterpret_cast<const v4f*>(x + (size_t)wave * Dn);
    const v4f* wr = reinterpret_cast<const v4f*>(ws);
    float acc = 0.0f;
    #pragma unroll
    for (int j = 0; j < 4; ++j) {
        // x is streamed exactly once (256MB >> L2): non-temporal to skip retention
        v4f xv = __builtin_nontemporal_load(&xr[lane + j * 64]);
        v4f wv = wr[lane + j * 64];   // 4KB, L1-resident
        acc += xv.x * wv.x + xv.y * wv.y + xv.z * wv.z + xv.w * wv.w;
    }
    #pragma unroll
    for (int off = 32; off; off >>= 1) acc += __shfl_xor(acc, off, 64);
    if (lane == 0) out[wave] = acc + ws[Dn];
}

extern "C" void kernel_launch(void* const* d_in, const int* in_sizes, int n_in,
                              void* d_out, int out_size, void* d_ws, size_t ws_size,
                              hipStream_t stream) {
    const float* x = (const float*)d_in[0];   // [B,T,D] fp32
    const float* W = (const float*)d_in[1];   // [D,D]  fp32
    const float* b = (const float*)d_in[2];   // [D]    fp32
    float* out = (float*)d_out;               // [B,T]  fp32
    float* ws  = (float*)d_ws;                // needs (D+1) floats = 4100 B

    sa_prep_kernel<<<33, 256, 0, stream>>>(W, b, ws);
    sa_dot_kernel<<<ROWS / 4, 256, 0, stream>>>(x, ws, out);
}